// Round 4
// baseline (37.569 us; speedup 1.0000x reference)
//
#include <hip/hip_runtime.h>

// P=40000, DEG=16, CI=CO=16.
// Single fused kernel (no workspace, no inter-kernel dependency):
//   out[p][o] = sum_n sum_d r[p,n,d] * (sum_i W[d][o][i] * feat[nbr(p,n)][i])
// Per-thread (p,o): W rows for channel o held in 48 VGPRs (loaded once from
// global, L1-broadcast across lanes); bs/radii staged in LDS per 16-point block.

__global__ __launch_bounds__(256) void k_fused(const float* __restrict__ feat,
                                               const float* __restrict__ radii,
                                               const float* __restrict__ W,
                                               const int* __restrict__ bs,
                                               float* __restrict__ out,
                                               int P) {
    __shared__ int   s_nbr[16][16];
    __shared__ float s_r[16][48];     // [local point][n*3 + d]
    const int tid = threadIdx.x;
    const int pbase = blockIdx.x * 16;

    // Stage neighbor indices: thread t -> (lp = t>>4, n = t&15).
    {
        const int lp = tid >> 4, n = tid & 15;
        const int p = pbase + lp;
        s_nbr[lp][n] = (p < P) ? bs[(size_t)p * 17 + 1 + n] : 0;
    }
    // Stage radii rows: 768 consecutive floats, coalesced.
    {
        float* srf = &s_r[0][0];
        const size_t lim = (size_t)P * 48;
        for (int t = tid; t < 768; t += 256) {
            const size_t gi = (size_t)pbase * 48 + t;
            srf[t] = (gi < lim) ? radii[gi] : 0.f;
        }
    }

    const int lp = tid >> 4, o = tid & 15;

    // W[d][o][0..15] for this thread's output channel, in registers.
    // W flat layout [3][16][16]: element (d,o,i) at d*256 + o*16 + i.
    float w0[16], w1[16], w2[16];
    {
        const float4* Wv = reinterpret_cast<const float4*>(W);
        const int base = o * 4;          // float4 units: (o*16)/4
#pragma unroll
        for (int j = 0; j < 4; ++j) {
            const float4 q0 = Wv[base + j];            // d=0
            const float4 q1 = Wv[64 + base + j];       // d=1 (256 floats = 64 float4)
            const float4 q2 = Wv[128 + base + j];      // d=2
            w0[j*4+0]=q0.x; w0[j*4+1]=q0.y; w0[j*4+2]=q0.z; w0[j*4+3]=q0.w;
            w1[j*4+0]=q1.x; w1[j*4+1]=q1.y; w1[j*4+2]=q1.z; w1[j*4+3]=q1.w;
            w2[j*4+0]=q2.x; w2[j*4+1]=q2.y; w2[j*4+2]=q2.z; w2[j*4+3]=q2.w;
        }
    }

    __syncthreads();

    const int p = pbase + lp;
    if (p >= P) return;

    float acc = 0.f;
#pragma unroll 4
    for (int n = 0; n < 16; ++n) {
        const int src = s_nbr[lp][n];
        const float4* f4 = reinterpret_cast<const float4*>(feat + (size_t)src * 16);
        const float4 A = f4[0], B = f4[1], C = f4[2], D = f4[3];
        float f[16];
        f[0]=A.x;  f[1]=A.y;  f[2]=A.z;  f[3]=A.w;
        f[4]=B.x;  f[5]=B.y;  f[6]=B.z;  f[7]=B.w;
        f[8]=C.x;  f[9]=C.y;  f[10]=C.z; f[11]=C.w;
        f[12]=D.x; f[13]=D.y; f[14]=D.z; f[15]=D.w;

        float s0 = 0.f, s1 = 0.f, s2 = 0.f;
#pragma unroll
        for (int i = 0; i < 16; ++i) {
            const float fi = f[i];
            s0 += w0[i] * fi;
            s1 += w1[i] * fi;
            s2 += w2[i] * fi;
        }
        acc += s_r[lp][n * 3 + 0] * s0
             + s_r[lp][n * 3 + 1] * s1
             + s_r[lp][n * 3 + 2] * s2;
    }
    out[(size_t)p * 16 + o] = acc;
}

extern "C" void kernel_launch(void* const* d_in, const int* in_sizes, int n_in,
                              void* d_out, int out_size, void* d_ws, size_t ws_size,
                              hipStream_t stream) {
    const float* feat  = (const float*)d_in[0];   // [P,16] f32
    const float* radii = (const float*)d_in[1];   // [E,3]  f32
    const float* W     = (const float*)d_in[2];   // [3,16,16] f32
    const int*   bs    = (const int*)d_in[3];     // [P,17] i32
    float* out = (float*)d_out;                   // [P,16] f32

    const int P = in_sizes[0] / 16;
    const int grid = (P + 15) / 16;
    k_fused<<<grid, 256, 0, stream>>>(feat, radii, W, bs, out, P);
}

// Round 5
// 13.846 us; speedup vs baseline: 2.7132x; 2.7132x over previous
//
#include <hip/hip_runtime.h>

// P=40000, DEG=16, CI=CO=16.
// Single kernel, no workspace. Contraction reordered:
//   h[p][d][i] = sum_n r[p,n,d] * feat[nbr(p,n)][i]     (edge loop: feat only)
//   out[p][o]  = sum_d sum_i W[d][o][i] * h[p][d][i]    (once per point)
// Block = 256 threads = 16 points. Phase A: thread (lp, i) accumulates h.
// Phase B (after LDS transpose): thread (lp, o) contracts with W.

__global__ __launch_bounds__(256) void k_conv(const float* __restrict__ feat,
                                              const float* __restrict__ radii,
                                              const float* __restrict__ W,
                                              const int* __restrict__ bs,
                                              float* __restrict__ out,
                                              int P) {
    __shared__ float s_Wt[3][16][16];  // s_Wt[d][i][o] = W[d][o][i]
    __shared__ int   s_nbr[16][16];    // [lp][n]
    __shared__ float s_r[16][48];      // [lp][n*3+d]
    __shared__ float s_h[16][48];      // [lp][d*16+i]

    const int tid = threadIdx.x;
    const int pbase = blockIdx.x * 16;
    const int lp = tid >> 4;           // local point 0..15
    const int li = tid & 15;           // i (phase A) / o (phase B)

    // --- stage W transposed: 768 floats ---
    for (int t = tid; t < 768; t += 256) {
        const int d = t >> 8;
        const int o = (t >> 4) & 15;
        const int i = t & 15;
        s_Wt[d][i][o] = W[t];          // W flat [3][16][16] row-major
    }
    // --- stage neighbor indices ---
    {
        const int p = pbase + lp;
        s_nbr[lp][li] = (p < P) ? bs[(size_t)p * 17 + 1 + li] : 0;
    }
    // --- stage radii rows: 768 consecutive floats, coalesced ---
    {
        float* srf = &s_r[0][0];
        const size_t lim = (size_t)P * 48;
        for (int t = tid; t < 768; t += 256) {
            const size_t gi = (size_t)pbase * 48 + t;
            srf[t] = (gi < lim) ? radii[gi] : 0.f;
        }
    }
    __syncthreads();

    // --- Phase A: h[lp][d][li] = sum_n r[lp][n][d] * feat[nbr][li] ---
    float h0 = 0.f, h1 = 0.f, h2 = 0.f;
#pragma unroll
    for (int n = 0; n < 16; ++n) {
        const int src = s_nbr[lp][n];                 // broadcast across 16 i-lanes
        const float fv = feat[(size_t)src * 16 + li]; // 64-B coalesced row read
        h0 += s_r[lp][n * 3 + 0] * fv;
        h1 += s_r[lp][n * 3 + 1] * fv;
        h2 += s_r[lp][n * 3 + 2] * fv;
    }
    s_h[lp][li]      = h0;
    s_h[lp][16 + li] = h1;
    s_h[lp][32 + li] = h2;
    __syncthreads();

    // --- Phase B: out[p][o] = sum_{d,i} Wt[d][i][o] * h[lp][d*16+i] ---
    const int p = pbase + lp;
    if (p >= P) return;

    float acc = 0.f;
#pragma unroll
    for (int d = 0; d < 3; ++d) {
#pragma unroll
        for (int i = 0; i < 16; ++i) {
            acc += s_Wt[d][i][li] * s_h[lp][d * 16 + i];
        }
    }
    out[(size_t)p * 16 + li] = acc;
}

extern "C" void kernel_launch(void* const* d_in, const int* in_sizes, int n_in,
                              void* d_out, int out_size, void* d_ws, size_t ws_size,
                              hipStream_t stream) {
    const float* feat  = (const float*)d_in[0];   // [P,16] f32
    const float* radii = (const float*)d_in[1];   // [E,3]  f32
    const float* W     = (const float*)d_in[2];   // [3,16,16] f32
    const int*   bs    = (const int*)d_in[3];     // [P,17] i32
    float* out = (float*)d_out;                   // [P,16] f32

    const int P = in_sizes[0] / 16;
    const int grid = (P + 15) / 16;
    k_conv<<<grid, 256, 0, stream>>>(feat, radii, W, bs, out, P);
}